// Round 6
// baseline (429.489 us; speedup 1.0000x reference)
//
#include <hip/hip_runtime.h>

#define HD 128  // hidden/feature dim (fixed by problem)

typedef _Float16 f16x8 __attribute__((ext_vector_type(8)));
typedef _Float16 f16x2 __attribute__((ext_vector_type(2)));
typedef float f32x4 __attribute__((ext_vector_type(4)));

// ---------------- degree count + per-edge slot (both graphs) ----------------
// slot[e] = old degree (ushort) -> csr fill needs no atomics. 4 edges/thread
// (vs 8 in prior round): 2x the waves in flight for the latency-bound
// returning atomics.
__global__ void k_deg_slot(const int* __restrict__ ei0, const int* __restrict__ ei1,
                           int E, int N, int* __restrict__ deg2,
                           unsigned short* __restrict__ slot) {
  int g = blockIdx.y;
  const int* rows = g ? ei1 : ei0;
  int* deg = deg2 + g * N;
  unsigned short* sl = slot + (size_t)g * E;
  int base = (blockIdx.x * 256 + threadIdx.x) * 4;
  if (base + 3 < E) {
    int4 r = *(const int4*)(rows + base);
    union { unsigned short us[4]; uint2 v; } s;
    s.us[0] = (unsigned short)atomicAdd(&deg[r.x], 1);
    s.us[1] = (unsigned short)atomicAdd(&deg[r.y], 1);
    s.us[2] = (unsigned short)atomicAdd(&deg[r.z], 1);
    s.us[3] = (unsigned short)atomicAdd(&deg[r.w], 1);
    *(uint2*)(sl + base) = s.v;
  } else {
    for (int e = base; e < E; ++e)
      sl[e] = (unsigned short)atomicAdd(&deg[rows[e]], 1);
  }
}

// ---------------- CSR fill: no atomics (uses ushort slot) ----------------
__global__ void k_csr_fill(const int* __restrict__ ei0, const int* __restrict__ ei1,
                           int E, int N, const int* __restrict__ offs,
                           const unsigned short* __restrict__ slot,
                           unsigned short* __restrict__ csr_col) {
  int g = blockIdx.y;
  const int* eg = (g ? ei1 : ei0);
  const int* ob = offs + g * N;
  const unsigned short* sl = slot + (size_t)g * E;
  int base = (blockIdx.x * 256 + threadIdx.x) * 4;
  if (base + 3 < E) {
    int4 r = *(const int4*)(eg + base);
    int4 c = *(const int4*)(eg + E + base);
    uint2 sv = *(const uint2*)(sl + base);
    csr_col[ob[r.x] + (sv.x & 0xffff)] = (unsigned short)c.x;
    csr_col[ob[r.y] + (sv.x >> 16)]    = (unsigned short)c.y;
    csr_col[ob[r.z] + (sv.y & 0xffff)] = (unsigned short)c.z;
    csr_col[ob[r.w] + (sv.y >> 16)]    = (unsigned short)c.w;
  } else {
    for (int e = base; e < E; ++e)
      csr_col[ob[eg[e]] + sl[e]] = (unsigned short)eg[E + e];
  }
}

// ---------------- GEMM block role: C = op(A @ W + b) (*scale[row]) ----------------
// W fp32 (k-major) staged in-kernel into LDS f16 in MFMA-fragment order.
// wave = 64 rows x 128 cols (4 m-tiles); block = 4 waves = 256 rows.
template<bool RELU, bool SCALE, bool CVT>
__device__ __forceinline__ void gemm_block(
    _Float16* lds, int bi,
    const _Float16* __restrict__ Ab, const float* __restrict__ Af0,
    const float* __restrict__ Af1, const float* __restrict__ Wg,
    const float* __restrict__ bias, const float* __restrict__ scale,
    _Float16* __restrict__ C, int N, int Ntot) {
  const int tid = threadIdx.x;
  // stage W: fp32 [k][n] -> LDS f16 at [((nt*4+kc)*64 + 16*q + n16)*8 + j]
  // where n = 16*nt + n16, k = 32*kc + 8*q + j.
  #pragma unroll
  for (int i = 0; i < 16; ++i) {
    int flat = i * 1024 + tid * 4;
    int k = flat >> 7, n0 = flat & 127;
    float4 w4 = *(const float4*)(Wg + flat);
    int kc = k >> 5, q = (k >> 3) & 3, j = k & 7;
    float wv[4] = {w4.x, w4.y, w4.z, w4.w};
    #pragma unroll
    for (int d = 0; d < 4; ++d) {
      int n = n0 + d;
      lds[(size_t)(((n >> 4) * 4 + kc) * 64 + 16 * q + (n & 15)) * 8 + j] = (_Float16)wv[d];
    }
  }
  __syncthreads();

  const int lane = tid & 63;
  const int wave = tid >> 6;
  const int n16 = lane & 15, q = lane >> 4;
  const int rowbase = bi * 256 + wave * 64;

  int arow[4];
  #pragma unroll
  for (int t = 0; t < 4; ++t) {
    int r = rowbase + 16 * t + n16;
    arow[t] = (r < Ntot) ? r : (Ntot - 1);
  }

  f32x4 acc[4][8];
  #pragma unroll
  for (int t = 0; t < 4; ++t)
    #pragma unroll
    for (int nt = 0; nt < 8; ++nt) acc[t][nt] = (f32x4){0.f, 0.f, 0.f, 0.f};

  #pragma unroll
  for (int kc = 0; kc < 4; ++kc) {
    f16x8 a[4];
    #pragma unroll
    for (int t = 0; t < 4; ++t) {
      if (CVT) {
        int r = arow[t];
        const float* src = (r < N) ? (Af0 + (size_t)r * HD) : (Af1 + (size_t)(r - N) * HD);
        float4 u0 = *(const float4*)(src + kc * 32 + q * 8);
        float4 u1 = *(const float4*)(src + kc * 32 + q * 8 + 4);
        union { _Float16 h[8]; f16x8 v; } tmp;
        tmp.h[0] = (_Float16)u0.x; tmp.h[1] = (_Float16)u0.y;
        tmp.h[2] = (_Float16)u0.z; tmp.h[3] = (_Float16)u0.w;
        tmp.h[4] = (_Float16)u1.x; tmp.h[5] = (_Float16)u1.y;
        tmp.h[6] = (_Float16)u1.z; tmp.h[7] = (_Float16)u1.w;
        a[t] = tmp.v;
      } else {
        a[t] = *(const f16x8*)(Ab + (size_t)arow[t] * HD + kc * 32 + q * 8);
      }
    }
    #pragma unroll
    for (int nt = 0; nt < 8; ++nt) {
      f16x8 b = *(const f16x8*)&lds[(size_t)((nt * 4 + kc) * 64 + lane) * 8];
      #pragma unroll
      for (int t = 0; t < 4; ++t)
        acc[t][nt] = __builtin_amdgcn_mfma_f32_16x16x32_f16(a[t], b, acc[t][nt], 0, 0, 0);
    }
  }

  float bv[8];
  #pragma unroll
  for (int nt = 0; nt < 8; ++nt) bv[nt] = bias[nt * 16 + n16];

  #pragma unroll
  for (int t = 0; t < 4; ++t) {
    #pragma unroll
    for (int r = 0; r < 4; ++r) {
      int row = rowbase + 16 * t + 4 * q + r;
      if (row < Ntot) {
        float s = SCALE ? scale[row] : 1.0f;
        #pragma unroll
        for (int nt = 0; nt < 8; ++nt) {
          float v = acc[t][nt][r] + bv[nt];
          if (RELU) v = fmaxf(v, 0.f);
          if (SCALE) v *= s;
          C[(size_t)row * HD + nt * 16 + n16] = (_Float16)v;
        }
      }
    }
  }
}

// ---------------- fused GEMM + aux role ----------------
// AUX: 0 none, 1 scan_block(+dis), 2 scan_partials (512 entries, 1 block),
// 3 scan_finalize (offs += partials). Aux roles reuse the GEMM LDS.
template<bool RELU, bool SCALE, bool CVT, int AUX>
__global__ __launch_bounds__(256, 2) void k_gemm_aux(
    const _Float16* __restrict__ Ab, const float* __restrict__ Af0,
    const float* __restrict__ Af1, const float* __restrict__ Wg,
    const float* __restrict__ bias, const float* __restrict__ scale,
    _Float16* __restrict__ C, int N, int Ntot, int gemmBlocks,
    const int* __restrict__ deg, int* __restrict__ offs,
    int* __restrict__ partials, float* __restrict__ dis,
    int scanBlocks, int Etot) {
  __shared__ _Float16 lds[16384];  // 32 KB
  int bi = blockIdx.x;
  if (bi < gemmBlocks) {
    gemm_block<RELU, SCALE, CVT>(lds, bi, Ab, Af0, Af1, Wg, bias, scale, C, N, Ntot);
    return;
  }
  int b = bi - gemmBlocks;
  int t = threadIdx.x;
  if (AUX == 1) {          // per-block exclusive scan of deg + dis = deg^-1/2
    int* s = (int*)lds;
    int i = b * 256 + t;
    int v = (i < Ntot) ? deg[i] : 0;
    s[t] = v;
    __syncthreads();
    #pragma unroll
    for (int off = 1; off < 256; off <<= 1) {
      int x = (t >= off) ? s[t - off] : 0;
      __syncthreads();
      s[t] += x;
      __syncthreads();
    }
    if (i < Ntot) {
      offs[i] = s[t] - v;
      dis[i] = (v > 0) ? (1.0f / sqrtf((float)v)) : 0.0f;
    }
    if (t == 255) partials[b] = s[255];
  } else if (AUX == 2) {   // exclusive scan of partials[0..scanBlocks), <=512
    int* s = (int*)lds;
    int P = scanBlocks;
    int v0 = (t < P) ? partials[t] : 0;
    int v1 = (t + 256 < P) ? partials[t + 256] : 0;
    s[t] = v0;
    s[t + 256] = v1;
    __syncthreads();
    #pragma unroll
    for (int off = 1; off < 256; off <<= 1) {
      int x0 = (t >= off) ? s[t - off] : 0;
      int x1 = (t >= off) ? s[256 + t - off] : 0;
      __syncthreads();
      s[t] += x0;
      s[256 + t] += x1;
      __syncthreads();
    }
    int tot0 = s[255];
    if (t < P) partials[t] = s[t] - v0;
    if (t + 256 < P) partials[t + 256] = s[256 + t] + tot0 - v1;
  } else if (AUX == 3) {   // finalize offs
    int i = b * 256 + t;
    if (i < Ntot) offs[i] += partials[b];
    if (b == 0 && t == 0) offs[Ntot] = Etot;
  }
}

// ---------------- CSR aggregate: out[r] = relu(dis[r]*sum T[col]) ----------------
// one wave/node; 16 lanes/row (uint4 = 8 f16/lane), 4 edges per gather instr.
// Messages accumulated as packed f16 pairs; final reduce fp32.
template<bool POOL>
__global__ __launch_bounds__(256) void k_aggregate(
    const _Float16* __restrict__ T, const int* __restrict__ offs,
    const unsigned short* __restrict__ csr_col, const float* __restrict__ dis,
    _Float16* __restrict__ out, float* __restrict__ poolrep, int N, int Ntot) {
  __shared__ float red[4][128];
  const int lane = threadIdx.x & 63;
  const int wave = threadIdx.x >> 6;
  const int gw = blockIdx.x * 4 + wave;
  const int sub = lane >> 4, c16 = lane & 15;

  f16x2 hacc[4];
  #pragma unroll
  for (int j = 0; j < 4; ++j) hacc[j] = (f16x2){(_Float16)0.f, (_Float16)0.f};

  if (gw < Ntot) {
    const int beg = offs[gw], end = offs[gw + 1];
    const uint4* Tg = (const uint4*)(T + (size_t)(gw >= N ? N : 0) * HD);
    for (int e = beg; e < end; e += 16) {
      uint4 v[4];
      #pragma unroll
      for (int gp = 0; gp < 4; ++gp) {
        v[gp] = make_uint4(0, 0, 0, 0);
        if (e + 4 * gp < end) {              // wave-uniform
          int eg = e + 4 * gp + sub;
          bool valid = (eg < end);
          int ce = valid ? eg : (end - 1);
          int col = csr_col[ce];
          uint4 t = Tg[(size_t)col * 16 + c16];
          if (valid) v[gp] = t;
        }
      }
      #pragma unroll
      for (int gp = 0; gp < 4; ++gp) {
        union { uint4 u; f16x2 h[4]; } w;
        w.u = v[gp];
        hacc[0] += w.h[0];
        hacc[1] += w.h[1];
        hacc[2] += w.h[2];
        hacc[3] += w.h[3];
      }
    }
  }

  float ax[8];
  #pragma unroll
  for (int j = 0; j < 4; ++j) {
    ax[2 * j]     = (float)hacc[j][0];
    ax[2 * j + 1] = (float)hacc[j][1];
  }
  #pragma unroll
  for (int j = 0; j < 8; ++j) {
    ax[j] += __shfl_xor(ax[j], 32, 64);
    ax[j] += __shfl_xor(ax[j], 16, 64);
  }
  float dr = (gw < Ntot) ? dis[gw] : 0.f;
  #pragma unroll
  for (int j = 0; j < 8; ++j) ax[j] = fmaxf(ax[j] * dr, 0.f);

  if (!POOL) {
    if (gw < Ntot && sub == 0) {
      union { uint4 u; _Float16 h[8]; } o;
      #pragma unroll
      for (int j = 0; j < 8; ++j) o.h[j] = (_Float16)ax[j];
      ((uint4*)out)[(size_t)gw * 16 + c16] = o.u;
    }
  } else {
    if (sub == 0) {
      *(float4*)&red[wave][c16 * 8]     = make_float4(ax[0], ax[1], ax[2], ax[3]);
      *(float4*)&red[wave][c16 * 8 + 4] = make_float4(ax[4], ax[5], ax[6], ax[7]);
    }
    __syncthreads();
    int t = threadIdx.x;
    if (t < 128) {
      float s = red[0][t] + red[1][t] + red[2][t] + red[3][t];
      int g = (blockIdx.x * 4 >= N) ? 1 : 0;
      atomicAdd(&poolrep[(size_t)((blockIdx.x & 15) * 2 + g) * 128 + t], s);
    }
  }
}

// ---------------- final similarity MLP (tiny, fp32) ----------------
__global__ void k_final(const float* __restrict__ poolrep,
                        const float* __restrict__ W1, const float* __restrict__ b1,
                        const float* __restrict__ W2, const float* __restrict__ b2,
                        float* __restrict__ out, float invN) {
  __shared__ float cs[512];
  __shared__ float red[2];
  int t = threadIdx.x;  // 128 threads
  float g1 = 0.f, g2 = 0.f;
  #pragma unroll
  for (int r = 0; r < 16; ++r) {
    g1 += poolrep[r * 256 + t];
    g2 += poolrep[r * 256 + 128 + t];
  }
  g1 *= invN;
  g2 *= invN;
  cs[t] = g1;
  cs[128 + t] = g2;
  cs[256 + t] = fabsf(g1 - g2);
  cs[384 + t] = g1 * g2;
  __syncthreads();
  float acc = b1[t];
  #pragma unroll 8
  for (int i = 0; i < 512; ++i) acc = fmaf(cs[i], W1[(size_t)i * HD + t], acc);
  float h = fmaxf(acc, 0.f);
  float v = h * W2[t];
  #pragma unroll
  for (int off = 32; off > 0; off >>= 1) v += __shfl_down(v, off, 64);
  if ((t & 63) == 0) red[t >> 6] = v;
  __syncthreads();
  if (t == 0) out[0] = red[0] + red[1] + b2[0];
}

extern "C" void kernel_launch(void* const* d_in, const int* in_sizes, int n_in,
                              void* d_out, int out_size, void* d_ws, size_t ws_size,
                              hipStream_t stream) {
  const float* x1     = (const float*)d_in[0];
  const int*   ei1    = (const int*)d_in[1];
  const float* x2     = (const float*)d_in[2];
  const int*   ei2    = (const int*)d_in[3];
  const float* W_in[4] = {(const float*)d_in[4], (const float*)d_in[6],
                          (const float*)d_in[8], (const float*)d_in[10]};
  const float* B_in[4] = {(const float*)d_in[5], (const float*)d_in[7],
                          (const float*)d_in[9], (const float*)d_in[11]};
  const float* sim_w1 = (const float*)d_in[12];
  const float* sim_b1 = (const float*)d_in[13];
  const float* sim_w2 = (const float*)d_in[14];
  const float* sim_b2 = (const float*)d_in[15];

  const int N = in_sizes[0] / HD;
  const int E = in_sizes[1] / 2;
  const int Ntot = 2 * N;

  // workspace layout (16B-aligned chunks first)
  _Float16* sp = (_Float16*)d_ws;
  _Float16* bufA = sp; sp += (size_t)Ntot * HD;
  _Float16* bufB = sp; sp += (size_t)Ntot * HD;
  float* fp = (float*)sp;
  float* dis     = fp; fp += Ntot;
  float* poolrep = fp; fp += 16 * 256;   // zeroed together with deg2 (adjacent)
  int* ip = (int*)fp;
  int* deg2     = ip; ip += Ntot;
  int* offs     = ip; ip += Ntot + 1;
  int* partials = ip; ip += 512;
  // align to 16B for vector slot stores
  ip = (int*)(((uintptr_t)ip + 15) & ~(uintptr_t)15);
  unsigned short* slot = (unsigned short*)ip;       // 2E ushorts
  unsigned short* csr_col = slot + 2 * (size_t)E;   // 2E ushorts

  const int gemmBlocks = (Ntot + 255) / 256;        // 391
  const int scanBlocks = (Ntot + 255) / 256;        // 391 (<=512 required)
  const int aggBlocks  = (Ntot + 3) / 4;
  const dim3 edgeGrid(((E + 3) / 4 + 255) / 256, 2);

  // poolrep + deg2 are adjacent: one memset
  hipMemsetAsync(poolrep, 0, (16 * 256 + Ntot) * sizeof(float), stream);

  // 1) degree + slots (atomic-latency-bound; maximize waves)
  k_deg_slot<<<edgeGrid, 256, 0, stream>>>(ei1, ei2, E, N, deg2, slot);

  // 2) enc1 GEMM (fp32->f16 fused) || per-block scan + dis
  k_gemm_aux<true, false, true, 1><<<gemmBlocks + scanBlocks, 256, 0, stream>>>(
      nullptr, x1, x2, W_in[0], B_in[0], nullptr, bufA, N, Ntot, gemmBlocks,
      deg2, offs, partials, dis, scanBlocks, 2 * E);

  // 3) enc2 GEMM || partials scan (1 aux block)
  k_gemm_aux<false, false, false, 2><<<gemmBlocks + 1, 256, 0, stream>>>(
      bufA, nullptr, nullptr, W_in[1], B_in[1], nullptr, bufB, N, Ntot, gemmBlocks,
      deg2, offs, partials, dis, scanBlocks, 2 * E);

  // 4) conv1 GEMM (T = (h@W+b)*dis) || offs finalize
  k_gemm_aux<false, true, false, 3><<<gemmBlocks + scanBlocks, 256, 0, stream>>>(
      bufB, nullptr, nullptr, W_in[2], B_in[2], dis, bufA, N, Ntot, gemmBlocks,
      deg2, offs, partials, dis, scanBlocks, 2 * E);

  // 5) CSR fill (atomic-free scatter via slots)
  k_csr_fill<<<edgeGrid, 256, 0, stream>>>(ei1, ei2, E, N, offs, slot, csr_col);

  // 6) aggregate 1
  k_aggregate<false><<<aggBlocks, 256, 0, stream>>>(bufA, offs, csr_col, dis, bufB, nullptr, N, Ntot);

  // 7) conv2 GEMM
  k_gemm_aux<false, true, false, 0><<<gemmBlocks, 256, 0, stream>>>(
      bufB, nullptr, nullptr, W_in[3], B_in[3], dis, bufA, N, Ntot, gemmBlocks,
      deg2, offs, partials, dis, scanBlocks, 2 * E);

  // 8) aggregate 2 + fused mean pool
  k_aggregate<true><<<aggBlocks, 256, 0, stream>>>(bufA, offs, csr_col, dis, nullptr, poolrep, N, Ntot);

  // 9) final MLP
  k_final<<<1, 128, 0, stream>>>(poolrep, sim_w1, sim_b1, sim_w2, sim_b2,
                                 (float*)d_out, 1.0f / (float)N);
}

// Round 7
// 418.775 us; speedup vs baseline: 1.0256x; 1.0256x over previous
//
#include <hip/hip_runtime.h>

#define HD 128  // hidden/feature dim (fixed by problem)

typedef _Float16 f16x8 __attribute__((ext_vector_type(8)));
typedef _Float16 f16x2 __attribute__((ext_vector_type(2)));
typedef float f32x4 __attribute__((ext_vector_type(4)));

// ---------------- GEMM block role: C = op(A @ W + b) (*scale[row]) ----------------
// block = 256 (4 waves) = 128 rows; wave = 32 rows x 128 cols (2 m-tiles).
// WF16: W pre-converted f16 fragment-order (32 KB vector copy, conflict-free).
// else: W fp32 k-major, converted in-kernel (enc1 only, hidden under deg).
template<bool RELU, bool SCALE, bool CVT, bool WF16>
__device__ __forceinline__ void gemm_block(
    _Float16* lds, int bi,
    const _Float16* __restrict__ Ab, const float* __restrict__ Af0,
    const float* __restrict__ Af1, const void* __restrict__ Wsrc,
    const float* __restrict__ bias, const float* __restrict__ scale,
    _Float16* __restrict__ C, int N, int Ntot) {
  const int tid = threadIdx.x;
  if (WF16) {
    const _Float16* Wf = (const _Float16*)Wsrc;
    #pragma unroll
    for (int i = 0; i < 8; ++i)   // 16 B/lane contiguous: conflict-free b128
      *(float4*)&lds[tid * 8 + i * 2048] = *(const float4*)&Wf[tid * 8 + i * 2048];
  } else {
    const float* Wg = (const float*)Wsrc;
    #pragma unroll
    for (int i = 0; i < 16; ++i) {
      int flat = i * 1024 + tid * 4;
      int k = flat >> 7, n0 = flat & 127;
      float4 w4 = *(const float4*)(Wg + flat);
      int kc = k >> 5, q = (k >> 3) & 3, j = k & 7;
      float wv[4] = {w4.x, w4.y, w4.z, w4.w};
      #pragma unroll
      for (int d = 0; d < 4; ++d) {
        int n = n0 + d;
        lds[(size_t)(((n >> 4) * 4 + kc) * 64 + 16 * q + (n & 15)) * 8 + j] = (_Float16)wv[d];
      }
    }
  }
  __syncthreads();

  const int lane = tid & 63;
  const int wave = tid >> 6;
  const int n16 = lane & 15, q = lane >> 4;
  const int rowbase = bi * 128 + wave * 32;

  int arow[2];
  #pragma unroll
  for (int t = 0; t < 2; ++t) {
    int r = rowbase + 16 * t + n16;
    arow[t] = (r < Ntot) ? r : (Ntot - 1);
  }

  f32x4 acc[2][8];
  #pragma unroll
  for (int t = 0; t < 2; ++t)
    #pragma unroll
    for (int nt = 0; nt < 8; ++nt) acc[t][nt] = (f32x4){0.f, 0.f, 0.f, 0.f};

  #pragma unroll
  for (int kc = 0; kc < 4; ++kc) {
    f16x8 a[2];
    #pragma unroll
    for (int t = 0; t < 2; ++t) {
      if (CVT) {
        int r = arow[t];
        const float* src = (r < N) ? (Af0 + (size_t)r * HD) : (Af1 + (size_t)(r - N) * HD);
        float4 u0 = *(const float4*)(src + kc * 32 + q * 8);
        float4 u1 = *(const float4*)(src + kc * 32 + q * 8 + 4);
        union { _Float16 h[8]; f16x8 v; } tmp;
        tmp.h[0] = (_Float16)u0.x; tmp.h[1] = (_Float16)u0.y;
        tmp.h[2] = (_Float16)u0.z; tmp.h[3] = (_Float16)u0.w;
        tmp.h[4] = (_Float16)u1.x; tmp.h[5] = (_Float16)u1.y;
        tmp.h[6] = (_Float16)u1.z; tmp.h[7] = (_Float16)u1.w;
        a[t] = tmp.v;
      } else {
        a[t] = *(const f16x8*)(Ab + (size_t)arow[t] * HD + kc * 32 + q * 8);
      }
    }
    #pragma unroll
    for (int nt = 0; nt < 8; ++nt) {
      f16x8 b = *(const f16x8*)&lds[(size_t)((nt * 4 + kc) * 64 + lane) * 8];
      #pragma unroll
      for (int t = 0; t < 2; ++t)
        acc[t][nt] = __builtin_amdgcn_mfma_f32_16x16x32_f16(a[t], b, acc[t][nt], 0, 0, 0);
    }
  }

  float bv[8];
  #pragma unroll
  for (int nt = 0; nt < 8; ++nt) bv[nt] = bias[nt * 16 + n16];

  #pragma unroll
  for (int t = 0; t < 2; ++t) {
    #pragma unroll
    for (int r = 0; r < 4; ++r) {
      int row = rowbase + 16 * t + 4 * q + r;
      if (row < Ntot) {
        float s = SCALE ? scale[row] : 1.0f;
        #pragma unroll
        for (int nt = 0; nt < 8; ++nt) {
          float v = acc[t][nt][r] + bv[nt];
          if (RELU) v = fmaxf(v, 0.f);
          if (SCALE) v *= s;
          C[(size_t)row * HD + nt * 16 + n16] = (_Float16)v;
        }
      }
    }
  }
}

// ---------------- fused GEMM + aux roles ----------------
// blocks [0, auxN): aux role; blocks [auxN, auxN+gemmBlocks): gemm.
// AUX 1: deg_slot (2*degB blocks) then W f16 fragment-order convert (24 blocks).
// AUX 2: per-block exclusive scan of deg + dis.  AUX 3: scan of partials (1 block).
template<bool RELU, bool SCALE, bool CVT, bool WF16, int AUX>
__global__ __launch_bounds__(256, 4) void k_fused(
    const _Float16* __restrict__ Ab, const float* __restrict__ Af0,
    const float* __restrict__ Af1, const void* __restrict__ Wsrc,
    const float* __restrict__ bias, const float* __restrict__ scale,
    _Float16* __restrict__ C, int N, int Ntot, int auxN,
    const int* __restrict__ ei0, const int* __restrict__ ei1, int E,
    int* __restrict__ deg2, unsigned short* __restrict__ slot,
    const float* __restrict__ w1, const float* __restrict__ w2,
    const float* __restrict__ w3, _Float16* __restrict__ WfOut, int degB,
    int* __restrict__ offs, int* __restrict__ partials,
    float* __restrict__ dis, int scanBlocks) {
  __shared__ _Float16 lds[16384];  // 32 KB
  const int bi = blockIdx.x;
  const int t = threadIdx.x;
  if (bi >= auxN) {
    gemm_block<RELU, SCALE, CVT, WF16>(lds, bi - auxN, Ab, Af0, Af1, Wsrc,
                                       bias, scale, C, N, Ntot);
    return;
  }
  if (AUX == 1) {
    if (bi < 2 * degB) {   // degree + slot for graph g
      int g = (bi >= degB);
      int cb = bi - g * degB;
      const int* rows = g ? ei1 : ei0;
      int* deg = deg2 + g * N;
      unsigned short* sl = slot + (size_t)g * E;
      int base = (cb * 256 + t) * 4;
      if (base + 3 < E) {
        int4 r = *(const int4*)(rows + base);
        union { unsigned short us[4]; uint2 v; } s;
        s.us[0] = (unsigned short)atomicAdd(&deg[r.x], 1);
        s.us[1] = (unsigned short)atomicAdd(&deg[r.y], 1);
        s.us[2] = (unsigned short)atomicAdd(&deg[r.z], 1);
        s.us[3] = (unsigned short)atomicAdd(&deg[r.w], 1);
        *(uint2*)(sl + base) = s.v;
      } else {
        for (int e = base; e < E; ++e)
          sl[e] = (unsigned short)atomicAdd(&deg[rows[e]], 1);
      }
    } else {               // W1..W3 fp32 -> f16 fragment-order (8 elems/thread)
      int wb = bi - 2 * degB;          // 0..23
      int m = wb >> 3;                 // 0..2
      const float* Wg = (m == 0) ? w1 : (m == 1) ? w2 : w3;
      int idx0 = (wb & 7) * 2048 + t * 8;
      float4 u0 = *(const float4*)(Wg + idx0);
      float4 u1 = *(const float4*)(Wg + idx0 + 4);
      int k = idx0 >> 7, n0 = idx0 & 127;
      int kc = k >> 5, q2 = (k >> 3) & 3, j = k & 7;
      _Float16* dst = WfOut + (size_t)m * 16384;
      float vv[8] = {u0.x, u0.y, u0.z, u0.w, u1.x, u1.y, u1.z, u1.w};
      #pragma unroll
      for (int d = 0; d < 8; ++d) {
        int n = n0 + d;
        dst[(size_t)(((n >> 4) * 4 + kc) * 64 + 16 * q2 + (n & 15)) * 8 + j] = (_Float16)vv[d];
      }
    }
  } else if (AUX == 2) {   // per-block exclusive scan + dis
    int* s = (int*)lds;
    int i = bi * 256 + t;
    int v = (i < Ntot) ? deg2[i] : 0;
    s[t] = v;
    __syncthreads();
    #pragma unroll
    for (int off = 1; off < 256; off <<= 1) {
      int x = (t >= off) ? s[t - off] : 0;
      __syncthreads();
      s[t] += x;
      __syncthreads();
    }
    if (i < Ntot) {
      offs[i] = s[t] - v;
      dis[i] = (v > 0) ? (1.0f / sqrtf((float)v)) : 0.0f;
    }
    if (t == 255) partials[bi] = s[255];
  } else if (AUX == 3) {   // exclusive scan of partials[0..scanBlocks), <=512
    int* s = (int*)lds;
    int P = scanBlocks;
    int v0 = (t < P) ? partials[t] : 0;
    int v1 = (t + 256 < P) ? partials[t + 256] : 0;
    s[t] = v0;
    s[t + 256] = v1;
    __syncthreads();
    #pragma unroll
    for (int off = 1; off < 256; off <<= 1) {
      int x0 = (t >= off) ? s[t - off] : 0;
      int x1 = (t >= off) ? s[256 + t - off] : 0;
      __syncthreads();
      s[t] += x0;
      s[256 + t] += x1;
      __syncthreads();
    }
    int tot0 = s[255];
    if (t < P) partials[t] = s[t] - v0;
    if (t + 256 < P) partials[t + 256] = s[256 + t] + tot0 - v1;
  }
}

// ---------------- CSR fill: no atomics; lazy offs = offs[n] + partials[n>>8] ------
__global__ void k_csr_fill(const int* __restrict__ ei0, const int* __restrict__ ei1,
                           int E, int N, const int* __restrict__ offs,
                           const int* __restrict__ partials,
                           const unsigned short* __restrict__ slot,
                           unsigned short* __restrict__ csr_col) {
  int g = blockIdx.y;
  const int* eg = (g ? ei1 : ei0);
  const int* ob = offs + g * N;
  const int* pb = partials;
  const unsigned short* sl = slot + (size_t)g * E;
  int gN = g * N;
  int base = (blockIdx.x * 256 + threadIdx.x) * 4;
  if (base + 3 < E) {
    int4 r = *(const int4*)(eg + base);
    int4 c = *(const int4*)(eg + E + base);
    uint2 sv = *(const uint2*)(sl + base);
    csr_col[ob[r.x] + pb[(gN + r.x) >> 8] + (sv.x & 0xffff)] = (unsigned short)c.x;
    csr_col[ob[r.y] + pb[(gN + r.y) >> 8] + (sv.x >> 16)]    = (unsigned short)c.y;
    csr_col[ob[r.z] + pb[(gN + r.z) >> 8] + (sv.y & 0xffff)] = (unsigned short)c.z;
    csr_col[ob[r.w] + pb[(gN + r.w) >> 8] + (sv.y >> 16)]    = (unsigned short)c.w;
  } else {
    for (int e = base; e < E; ++e)
      csr_col[ob[eg[e]] + pb[(gN + eg[e]) >> 8] + sl[e]] = (unsigned short)eg[E + e];
  }
}

// ---------------- CSR aggregate: out[r] = relu(dis[r]*sum T[col]) ----------------
// one wave/node; 16 lanes/row (uint4 = 8 f16/lane); packed-f16 accumulate.
template<bool POOL>
__global__ __launch_bounds__(256) void k_aggregate(
    const _Float16* __restrict__ T, const int* __restrict__ offs,
    const int* __restrict__ partials, const unsigned short* __restrict__ csr_col,
    const float* __restrict__ dis, _Float16* __restrict__ out,
    float* __restrict__ poolrep, int N, int Ntot, int Etot) {
  __shared__ float red[4][128];
  const int lane = threadIdx.x & 63;
  const int wave = threadIdx.x >> 6;
  const int gw = blockIdx.x * 4 + wave;
  const int sub = lane >> 4, c16 = lane & 15;

  f16x2 hacc[4];
  #pragma unroll
  for (int j = 0; j < 4; ++j) hacc[j] = (f16x2){(_Float16)0.f, (_Float16)0.f};

  if (gw < Ntot) {
    const int beg = offs[gw] + partials[gw >> 8];
    const int end = (gw + 1 == Ntot) ? Etot : (offs[gw + 1] + partials[(gw + 1) >> 8]);
    const uint4* Tg = (const uint4*)(T + (size_t)(gw >= N ? N : 0) * HD);
    for (int e = beg; e < end; e += 16) {
      uint4 v[4];
      #pragma unroll
      for (int gp = 0; gp < 4; ++gp) {
        v[gp] = make_uint4(0, 0, 0, 0);
        if (e + 4 * gp < end) {              // wave-uniform
          int eg = e + 4 * gp + sub;
          bool valid = (eg < end);
          int ce = valid ? eg : (end - 1);
          int col = csr_col[ce];
          uint4 tv = Tg[(size_t)col * 16 + c16];
          if (valid) v[gp] = tv;
        }
      }
      #pragma unroll
      for (int gp = 0; gp < 4; ++gp) {
        union { uint4 u; f16x2 h[4]; } w;
        w.u = v[gp];
        hacc[0] += w.h[0];
        hacc[1] += w.h[1];
        hacc[2] += w.h[2];
        hacc[3] += w.h[3];
      }
    }
  }

  float ax[8];
  #pragma unroll
  for (int j = 0; j < 4; ++j) {
    ax[2 * j]     = (float)hacc[j][0];
    ax[2 * j + 1] = (float)hacc[j][1];
  }
  #pragma unroll
  for (int j = 0; j < 8; ++j) {
    ax[j] += __shfl_xor(ax[j], 32, 64);
    ax[j] += __shfl_xor(ax[j], 16, 64);
  }
  float dr = (gw < Ntot) ? dis[gw] : 0.f;
  #pragma unroll
  for (int j = 0; j < 8; ++j) ax[j] = fmaxf(ax[j] * dr, 0.f);

  if (!POOL) {
    if (gw < Ntot && sub == 0) {
      union { uint4 u; _Float16 h[8]; } o;
      #pragma unroll
      for (int j = 0; j < 8; ++j) o.h[j] = (_Float16)ax[j];
      ((uint4*)out)[(size_t)gw * 16 + c16] = o.u;
    }
  } else {
    if (sub == 0) {
      *(float4*)&red[wave][c16 * 8]     = make_float4(ax[0], ax[1], ax[2], ax[3]);
      *(float4*)&red[wave][c16 * 8 + 4] = make_float4(ax[4], ax[5], ax[6], ax[7]);
    }
    __syncthreads();
    int t = threadIdx.x;
    if (t < 128) {
      float s = red[0][t] + red[1][t] + red[2][t] + red[3][t];
      int g = (blockIdx.x * 4 >= N) ? 1 : 0;
      atomicAdd(&poolrep[(size_t)((blockIdx.x & 15) * 2 + g) * 128 + t], s);
    }
  }
}

// ---------------- final similarity MLP (tiny, fp32) ----------------
__global__ void k_final(const float* __restrict__ poolrep,
                        const float* __restrict__ W1, const float* __restrict__ b1,
                        const float* __restrict__ W2, const float* __restrict__ b2,
                        float* __restrict__ out, float invN) {
  __shared__ float cs[512];
  __shared__ float red[2];
  int t = threadIdx.x;  // 128 threads
  float g1 = 0.f, g2 = 0.f;
  #pragma unroll
  for (int r = 0; r < 16; ++r) {
    g1 += poolrep[r * 256 + t];
    g2 += poolrep[r * 256 + 128 + t];
  }
  g1 *= invN;
  g2 *= invN;
  cs[t] = g1;
  cs[128 + t] = g2;
  cs[256 + t] = fabsf(g1 - g2);
  cs[384 + t] = g1 * g2;
  __syncthreads();
  float acc = b1[t];
  #pragma unroll 8
  for (int i = 0; i < 512; ++i) acc = fmaf(cs[i], W1[(size_t)i * HD + t], acc);
  float h = fmaxf(acc, 0.f);
  float v = h * W2[t];
  #pragma unroll
  for (int off = 32; off > 0; off >>= 1) v += __shfl_down(v, off, 64);
  if ((t & 63) == 0) red[t >> 6] = v;
  __syncthreads();
  if (t == 0) out[0] = red[0] + red[1] + b2[0];
}

extern "C" void kernel_launch(void* const* d_in, const int* in_sizes, int n_in,
                              void* d_out, int out_size, void* d_ws, size_t ws_size,
                              hipStream_t stream) {
  const float* x1     = (const float*)d_in[0];
  const int*   ei1    = (const int*)d_in[1];
  const float* x2     = (const float*)d_in[2];
  const int*   ei2    = (const int*)d_in[3];
  const float* W_in[4] = {(const float*)d_in[4], (const float*)d_in[6],
                          (const float*)d_in[8], (const float*)d_in[10]};
  const float* B_in[4] = {(const float*)d_in[5], (const float*)d_in[7],
                          (const float*)d_in[9], (const float*)d_in[11]};
  const float* sim_w1 = (const float*)d_in[12];
  const float* sim_b1 = (const float*)d_in[13];
  const float* sim_w2 = (const float*)d_in[14];
  const float* sim_b2 = (const float*)d_in[15];

  const int N = in_sizes[0] / HD;
  const int E = in_sizes[1] / 2;
  const int Ntot = 2 * N;

  // workspace layout (16B-aligned chunks first)
  _Float16* sp = (_Float16*)d_ws;
  _Float16* bufA = sp; sp += (size_t)Ntot * HD;
  _Float16* bufB = sp; sp += (size_t)Ntot * HD;
  _Float16* WfB  = sp; sp += 3 * 16384;           // enc2, conv1, conv2 frag-order f16
  float* fp = (float*)sp;
  float* dis     = fp; fp += Ntot;
  float* poolrep = fp; fp += 16 * 256;            // zeroed together with deg2 (adjacent)
  int* ip = (int*)fp;
  int* deg2     = ip; ip += Ntot;
  int* offs     = ip; ip += Ntot;
  int* partials = ip; ip += 512;
  // align to 16B for vector slot stores
  ip = (int*)(((uintptr_t)ip + 15) & ~(uintptr_t)15);
  unsigned short* slot = (unsigned short*)ip;       // 2E ushorts
  unsigned short* csr_col = slot + 2 * (size_t)E;   // 2E ushorts

  const int G = (Ntot + 127) / 128;                 // 782 gemm blocks
  const int scanB = (Ntot + 255) / 256;             // 391 (<=512 required)
  const int aggB  = (Ntot + 3) / 4;
  const int degB  = (E + 1023) / 1024;              // 782 per graph
  const dim3 fillGrid(((E + 3) / 4 + 255) / 256, 2);

  // poolrep + deg2 are adjacent: one memset
  hipMemsetAsync(poolrep, 0, (16 * 256 + Ntot) * sizeof(float), stream);

  // D1: deg_slot (atomic-rate-bound) + W1..3 convert + enc1 GEMM (hidden)
  {
    int auxN = 2 * degB + 24;
    k_fused<true, false, true, false, 1><<<auxN + G, 256, 0, stream>>>(
        nullptr, x1, x2, W_in[0], B_in[0], nullptr, bufA, N, Ntot, auxN,
        ei1, ei2, E, deg2, slot, W_in[1], W_in[2], W_in[3], WfB, degB,
        offs, partials, dis, scanB);
  }
  // D2: enc2 GEMM || per-block scan + dis
  k_fused<false, false, false, true, 2><<<scanB + G, 256, 0, stream>>>(
      bufA, nullptr, nullptr, WfB + 0 * 16384, B_in[1], nullptr, bufB, N, Ntot, scanB,
      nullptr, nullptr, E, deg2, nullptr, nullptr, nullptr, nullptr, nullptr, degB,
      offs, partials, dis, scanB);
  // D3: conv1 GEMM (T = (h@W+b)*dis) || partials scan (1 aux block)
  k_fused<false, true, false, true, 3><<<1 + G, 256, 0, stream>>>(
      bufB, nullptr, nullptr, WfB + 1 * 16384, B_in[2], dis, bufA, N, Ntot, 1,
      nullptr, nullptr, E, deg2, nullptr, nullptr, nullptr, nullptr, nullptr, degB,
      offs, partials, dis, scanB);
  // D4: CSR fill (atomic-free scatter; lazy offs)
  k_csr_fill<<<fillGrid, 256, 0, stream>>>(ei1, ei2, E, N, offs, partials, slot, csr_col);
  // D5: aggregate 1
  k_aggregate<false><<<aggB, 256, 0, stream>>>(bufA, offs, partials, csr_col, dis,
                                               bufB, nullptr, N, Ntot, 2 * E);
  // D6: conv2 GEMM
  k_fused<false, true, false, true, 0><<<G, 256, 0, stream>>>(
      bufB, nullptr, nullptr, WfB + 2 * 16384, B_in[3], dis, bufA, N, Ntot, 0,
      nullptr, nullptr, E, deg2, nullptr, nullptr, nullptr, nullptr, nullptr, degB,
      offs, partials, dis, scanB);
  // D7: aggregate 2 + fused mean pool
  k_aggregate<true><<<aggB, 256, 0, stream>>>(bufA, offs, partials, csr_col, dis,
                                              nullptr, poolrep, N, Ntot, 2 * E);
  // D8: final MLP
  k_final<<<1, 128, 0, stream>>>(poolrep, sim_w1, sim_b1, sim_w2, sim_b2,
                                 (float*)d_out, 1.0f / (float)N);
}